// Round 1
// baseline (523.525 us; speedup 1.0000x reference)
//
#include <hip/hip_runtime.h>

// CrossAttention fused pipeline for MI355X (gfx950).
// Stages: weight fp32->bf16 convert | LayerNorm+residual-copy | 6 fused QKV
// GEMMs (bf16 MFMA 16x16x32, 128x128 tiles) | flash-style cross-attention
// (bf16 MFMA QK^T + online softmax + PV), both directions.
// ws usage: ~113 MB (weights bf16 12MB, norms 25MB, QKV 75MB).

#define DIM 1024
#define HEADS 16
#define DK 64
#define BATCH 8
#define NTXT 512
#define NVIS 1024

typedef __attribute__((ext_vector_type(8))) short bf16x8;
typedef __attribute__((ext_vector_type(4))) float f32x4;
typedef __attribute__((ext_vector_type(4))) unsigned short u16x4;

__device__ inline unsigned short f2bf(float f) {
    unsigned u = __builtin_bit_cast(unsigned, f);
    u += 0x7fffu + ((u >> 16) & 1u);   // round-to-nearest-even
    return (unsigned short)(u >> 16);
}
__device__ inline float bf2f(unsigned short h) {
    unsigned u = ((unsigned)h) << 16;
    return __builtin_bit_cast(float, u);
}
__device__ inline f32x4 mfma16(bf16x8 a, bf16x8 b, f32x4 c) {
    return __builtin_amdgcn_mfma_f32_16x16x32_bf16(a, b, c, 0, 0, 0);
}

// ---------------------------------------------------------------- weights cvt
struct WPtrs { const float* w[6]; };

__global__ __launch_bounds__(256) void cvt_w_kernel(WPtrs p, unsigned short* __restrict__ out) {
    int g = blockIdx.y;
    int i = blockIdx.x * 256 + threadIdx.x;          // i indexes groups of 4 floats
    float4 v = ((const float4*)p.w[g])[i];
    u16x4 o;
    o[0] = f2bf(v.x); o[1] = f2bf(v.y); o[2] = f2bf(v.z); o[3] = f2bf(v.w);
    *(u16x4*)(out + (size_t)g * (DIM * DIM) + (size_t)i * 4) = o;
}

// ------------------------------------------------------- layernorm + residual
__global__ __launch_bounds__(256) void ln_copy_kernel(
        const float* __restrict__ x, const float* __restrict__ g,
        const float* __restrict__ bta, unsigned short* __restrict__ xn,
        float* __restrict__ res) {
    int row = blockIdx.x;
    int tid = threadIdx.x;
    const float4* xr = (const float4*)(x + (size_t)row * DIM);
    float4 v = xr[tid];                               // 256 threads * 4 = 1024
    float s = v.x + v.y + v.z + v.w;
    float ss = v.x * v.x + v.y * v.y + v.z * v.z + v.w * v.w;
#pragma unroll
    for (int m = 1; m < 64; m <<= 1) { s += __shfl_xor(s, m); ss += __shfl_xor(ss, m); }
    __shared__ float red[8];
    int wave = tid >> 6, lane = tid & 63;
    if (lane == 0) { red[wave] = s; red[4 + wave] = ss; }
    __syncthreads();
    s = red[0] + red[1] + red[2] + red[3];
    ss = red[4] + red[5] + red[6] + red[7];
    float mu = s * (1.0f / DIM);
    float var = ss * (1.0f / DIM) - mu * mu;
    float rinv = rsqrtf(var + 1e-5f);
    float4 gv = ((const float4*)g)[tid];
    float4 bv = ((const float4*)bta)[tid];
    ((float4*)(res + (size_t)row * DIM))[tid] = v;    // residual passthrough (fp32)
    u16x4 o;
    o[0] = f2bf((v.x - mu) * rinv * gv.x + bv.x);
    o[1] = f2bf((v.y - mu) * rinv * gv.y + bv.y);
    o[2] = f2bf((v.z - mu) * rinv * gv.z + bv.z);
    o[3] = f2bf((v.w - mu) * rinv * gv.w + bv.w);
    *(u16x4*)(xn + (size_t)row * DIM + tid * 4) = o;
}

// -------------------------------------------------------------- fused QKV GEMM
// C[m][n] = sum_k A[m][k] * W[n][k] + bias[n]   (NT layout: both row-major in k)
struct GemmParams {
    const unsigned short* A[2];      // [0]=t_norm (M=4096), [1]=v_norm (M=8192)
    const unsigned short* W;         // 6 contiguous bf16 weight matrices
    const float* bias[6];
    unsigned short* out[6];
};

__global__ __launch_bounds__(256) void gemm_qkv_kernel(GemmParams P) {
    int bid = blockIdx.x;
    int g, t;
    if (bid < 768) { g = bid >> 8; t = bid & 255; }          // text: 32x8 tiles each
    else { int r = bid - 768; g = 3 + (r >> 9); t = r & 511; } // vision: 64x8 tiles
    const unsigned short* A = P.A[g < 3 ? 0 : 1];
    int tm = t >> 3, tn = t & 7;
    const unsigned short* Ap = A + (size_t)tm * 128 * DIM;
    const unsigned short* Wp = P.W + (size_t)g * (DIM * DIM) + (size_t)tn * 128 * DIM;

    __shared__ __align__(16) unsigned short As[128][32];
    __shared__ __align__(16) unsigned short Bs[128][32];

    int tid = threadIdx.x;
    int wave = tid >> 6, lane = tid & 63;
    int wm = (wave & 1) * 64, wn = (wave >> 1) * 64;
    int col16 = lane & 15, quad = lane >> 4;

    f32x4 zero = {0.f, 0.f, 0.f, 0.f};
    f32x4 acc[4][4];
#pragma unroll
    for (int i = 0; i < 4; i++)
#pragma unroll
        for (int j = 0; j < 4; j++) acc[i][j] = zero;

    for (int k0 = 0; k0 < DIM; k0 += 32) {
        __syncthreads();
#pragma unroll
        for (int i = 0; i < 2; i++) {                 // 512 16B chunks / 256 thr
            int c = tid + i * 256;
            int row = c >> 2, koff = (c & 3) * 8;
            *(bf16x8*)&As[row][koff] = *(const bf16x8*)(Ap + (size_t)row * DIM + k0 + koff);
            *(bf16x8*)&Bs[row][koff] = *(const bf16x8*)(Wp + (size_t)row * DIM + k0 + koff);
        }
        __syncthreads();
        bf16x8 af[4], bfr[4];
#pragma unroll
        for (int mi = 0; mi < 4; mi++) af[mi] = *(const bf16x8*)&As[wm + mi * 16 + col16][quad * 8];
#pragma unroll
        for (int ni = 0; ni < 4; ni++) bfr[ni] = *(const bf16x8*)&Bs[wn + ni * 16 + col16][quad * 8];
#pragma unroll
        for (int mi = 0; mi < 4; mi++)
#pragma unroll
            for (int ni = 0; ni < 4; ni++)
                acc[mi][ni] = mfma16(af[mi], bfr[ni], acc[mi][ni]);
    }

    const float* bias = P.bias[g];
    unsigned short* out = P.out[g];
    float bv[4];
#pragma unroll
    for (int ni = 0; ni < 4; ni++) bv[ni] = bias[tn * 128 + wn + ni * 16 + col16];
#pragma unroll
    for (int mi = 0; mi < 4; mi++) {
#pragma unroll
        for (int reg = 0; reg < 4; reg++) {
            int row = tm * 128 + wm + mi * 16 + quad * 4 + reg;   // C/D: row=(l>>4)*4+reg
#pragma unroll
            for (int ni = 0; ni < 4; ni++) {
                out[(size_t)row * DIM + tn * 128 + wn + ni * 16 + col16] =
                    f2bf(acc[mi][ni][reg] + bv[ni]);
            }
        }
    }
}

// ------------------------------------------------------- flash cross-attention
// One block per (b, h, 64-row Q tile). 4 waves, each owns 16 Q rows.
__global__ __launch_bounds__(256) void attn_kernel(
        const unsigned short* __restrict__ Q, const unsigned short* __restrict__ K,
        const unsigned short* __restrict__ V, float* __restrict__ Out,
        int Nq, int Nkv) {
    int qtiles = Nq >> 6;
    int bid = blockIdx.x;
    int qt = bid % qtiles;
    int bh = bid / qtiles;
    int b = bh >> 4, h = bh & 15;
    int tid = threadIdx.x;
    int wave = tid >> 6, lane = tid & 63;
    int col16 = lane & 15, quad = lane >> 4;

    __shared__ float Vs[64][65];                       // V tile fp32, +1 pad
    __shared__ __align__(16) unsigned short Ps[4][16][72]; // per-wave P, pad 72

    // Q fragments (A-operand: m=lane&15, k=quad*8+j), held for whole K loop
    const unsigned short* qp =
        Q + ((size_t)(b * Nq + qt * 64 + wave * 16 + col16)) * DIM + h * DK;
    bf16x8 qfrag[2];
    qfrag[0] = *(const bf16x8*)(qp + quad * 8);
    qfrag[1] = *(const bf16x8*)(qp + 32 + quad * 8);

    f32x4 zero = {0.f, 0.f, 0.f, 0.f};
    f32x4 o[4];
#pragma unroll
    for (int d = 0; d < 4; d++) o[d] = zero;
    float mrow[4] = {-1e30f, -1e30f, -1e30f, -1e30f};
    float lrow[4] = {0.f, 0.f, 0.f, 0.f};
    const float scale = 0.125f;                        // 1/sqrt(64)

    int vn = tid >> 2;                                 // V staging: row 0..63
    int vd0 = (tid & 3) * 16;                          // 16-col chunk

    for (int nb = 0; nb < Nkv; nb += 64) {
        __syncthreads();                               // protect Vs (WAR)
        {
            const unsigned short* vp =
                V + ((size_t)(b * Nkv + nb + vn)) * DIM + h * DK + vd0;
            bf16x8 va = *(const bf16x8*)vp;
            bf16x8 vb = *(const bf16x8*)(vp + 8);
#pragma unroll
            for (int j = 0; j < 8; j++) {
                Vs[vn][vd0 + j] = bf2f((unsigned short)va[j]);
                Vs[vn][vd0 + 8 + j] = bf2f((unsigned short)vb[j]);
            }
        }
        __syncthreads();

        // S = Q K^T for 4 16-col key chunks
        float s[4][4];                                 // [ntile][reg]
#pragma unroll
        for (int nt = 0; nt < 4; nt++) {
            const unsigned short* kp =
                K + ((size_t)(b * Nkv + nb + nt * 16 + col16)) * DIM + h * DK;
            bf16x8 kf0 = *(const bf16x8*)(kp + quad * 8);
            bf16x8 kf1 = *(const bf16x8*)(kp + 32 + quad * 8);
            f32x4 c = zero;
            c = mfma16(qfrag[0], kf0, c);
            c = mfma16(qfrag[1], kf1, c);
#pragma unroll
            for (int reg = 0; reg < 4; reg++) s[nt][reg] = c[reg] * scale;
        }

        // online softmax; row r=quad*4+reg lives on the 16 lanes of this quad
#pragma unroll
        for (int reg = 0; reg < 4; reg++) {
            float mx = fmaxf(fmaxf(s[0][reg], s[1][reg]), fmaxf(s[2][reg], s[3][reg]));
#pragma unroll
            for (int mm = 1; mm < 16; mm <<= 1) mx = fmaxf(mx, __shfl_xor(mx, mm));
            float mnew = fmaxf(mrow[reg], mx);
            float alpha = __expf(mrow[reg] - mnew);
            mrow[reg] = mnew;
            float rs = 0.f;
#pragma unroll
            for (int nt = 0; nt < 4; nt++) {
                s[nt][reg] = __expf(s[nt][reg] - mnew);
                rs += s[nt][reg];
            }
#pragma unroll
            for (int mm = 1; mm < 16; mm <<= 1) rs += __shfl_xor(rs, mm);
            lrow[reg] = lrow[reg] * alpha + rs;
#pragma unroll
            for (int d = 0; d < 4; d++) o[d][reg] *= alpha;
#pragma unroll
            for (int nt = 0; nt < 4; nt++)
                Ps[wave][quad * 4 + reg][nt * 16 + col16] = f2bf(s[nt][reg]);
        }
        __syncthreads();                               // Ps ready (block barrier)

        // O += P V  (P via LDS round-trip into A-layout; V cols from Vs)
#pragma unroll
        for (int half = 0; half < 2; half++) {
            bf16x8 pf = *(const bf16x8*)&Ps[wave][col16][half * 32 + quad * 8];
#pragma unroll
            for (int d = 0; d < 4; d++) {
                bf16x8 vf;
#pragma unroll
                for (int j = 0; j < 8; j++)
                    vf[j] = (short)f2bf(Vs[half * 32 + quad * 8 + j][d * 16 + col16]);
                o[d] = mfma16(pf, vf, o[d]);
            }
        }
    }

    // epilogue: O /= l, write fp32 (out[b][n][h*64+d])
#pragma unroll
    for (int reg = 0; reg < 4; reg++) {
        int nrow = qt * 64 + wave * 16 + quad * 4 + reg;
        float inv = 1.0f / lrow[reg];
        float* op = Out + ((size_t)(b * Nq + nrow)) * DIM + h * DK;
#pragma unroll
        for (int d = 0; d < 4; d++) op[d * 16 + col16] = o[d][reg] * inv;
    }
}

// -------------------------------------------------------------------- launch
extern "C" void kernel_launch(void* const* d_in, const int* in_sizes, int n_in,
                              void* d_out, int out_size, void* d_ws, size_t ws_size,
                              hipStream_t stream) {
    const float* text   = (const float*)d_in[0];
    const float* vision = (const float*)d_in[1];
    const float* n1g = (const float*)d_in[2];
    const float* n1b = (const float*)d_in[3];
    const float* n2g = (const float*)d_in[4];
    const float* n2b = (const float*)d_in[5];
    const float* W[6];
    const float* bias[6];
    for (int i = 0; i < 6; i++) {
        W[i]    = (const float*)d_in[6 + 2 * i];
        bias[i] = (const float*)d_in[7 + 2 * i];
    }

    float* out = (float*)d_out;
    float* a1   = out;                 // (8,512,1024)
    float* a2   = out + 4194304;       // (8,1024,1024)
    float* tres = out + 12582912;      // (8,512,1024)
    float* vres = out + 16777216;      // (8,1024,1024)

    char* ws = (char*)d_ws;
    unsigned short* Wc  = (unsigned short*)(ws);              // 12.0 MB
    unsigned short* tno = (unsigned short*)(ws + 12582912);   //  8.0 MB
    unsigned short* vno = (unsigned short*)(ws + 20971520);   // 16.0 MB
    unsigned short* tq  = (unsigned short*)(ws + 37748736);
    unsigned short* tk  = (unsigned short*)(ws + 46137344);
    unsigned short* tv  = (unsigned short*)(ws + 54525952);
    unsigned short* vq  = (unsigned short*)(ws + 62914560);
    unsigned short* vk  = (unsigned short*)(ws + 79691776);
    unsigned short* vv  = (unsigned short*)(ws + 96468992);   // ends 113246208

    WPtrs wp;
    for (int i = 0; i < 6; i++) wp.w[i] = W[i];
    cvt_w_kernel<<<dim3(1024, 6), 256, 0, stream>>>(wp, Wc);
    ln_copy_kernel<<<4096, 256, 0, stream>>>(text, n1g, n1b, tno, tres);
    ln_copy_kernel<<<8192, 256, 0, stream>>>(vision, n2g, n2b, vno, vres);

    GemmParams gp;
    gp.A[0] = tno; gp.A[1] = vno; gp.W = Wc;
    for (int i = 0; i < 6; i++) gp.bias[i] = bias[i];
    gp.out[0] = tq; gp.out[1] = tk; gp.out[2] = tv;
    gp.out[3] = vq; gp.out[4] = vk; gp.out[5] = vv;
    gemm_qkv_kernel<<<2304, 256, 0, stream>>>(gp);

    // text queries -> vision K/V ; vision queries -> text K/V
    attn_kernel<<<1024, 256, 0, stream>>>(tq, vk, vv, a1, NTXT, NVIS);
    attn_kernel<<<2048, 256, 0, stream>>>(vq, tk, tv, a2, NVIS, NTXT);
}